// Round 7
// baseline (2575.413 us; speedup 1.0000x reference)
//
#include <hip/hip_runtime.h>
#include <hip/hip_bf16.h>
#include <math.h>

#define BB 32
#define SS 4096
#define EE 512
#define AA 512

typedef short bf16x8 __attribute__((ext_vector_type(8)));
typedef float f32x4 __attribute__((ext_vector_type(4)));
typedef unsigned short u16x4 __attribute__((ext_vector_type(4)));

__device__ __forceinline__ unsigned short f2bf(float f) {
  unsigned int u = __float_as_uint(f);
  u += 0x7fffu + ((u >> 16) & 1u);   // RNE (finite normals)
  return (unsigned short)(u >> 16);
}

__device__ __forceinline__ float bf2f(unsigned short s) {
  return __uint_as_float(((unsigned int)s) << 16);
}

__device__ __forceinline__ float tanh_fast(float x) {
  return 1.f - 2.f / (__expf(2.f * x) + 1.f);
}

// Merged prologue, role by blockIdx.x (unchanged from R6):
__global__ __launch_bounds__(512) void prep_kernel(
    const float* __restrict__ h, const float* __restrict__ Wh,
    const float* __restrict__ Ws, float* __restrict__ qpart,
    unsigned short* __restrict__ WF) {
  __shared__ float hrow[64];
  const int blk = blockIdx.x;
  const int t = threadIdx.x;
  if (blk < 256) {                      // ---- query partial ----
    const int b = blk >> 3, sl = blk & 7, e0 = sl * 64;
    if (t < 64) hrow[t] = h[b * EE + e0 + t];
    __syncthreads();
    float a = 0.f;
#pragma unroll 8
    for (int e = 0; e < 64; ++e) a += hrow[e] * Wh[(size_t)(e0 + e) * AA + t];
    qpart[(size_t)blk * AA + t] = a;
  } else {                              // ---- WF fragment-major B ----
    const int nb = blk - 256;
#pragma unroll
    for (int rep = 0; rep < 2; ++rep) {
      const int idx = rep * 512 + t;    // 0..1023 = kb*64 + lane
      const int kb = idx >> 6, lane = idx & 63;
      const int krow = kb * 32 + ((lane >> 4) << 3);
      const int acol = nb * 16 + (lane & 15);
      bf16x8 vv;
#pragma unroll
      for (int i = 0; i < 8; ++i)
        vv[i] = (short)f2bf(Ws[(size_t)(krow + i) * AA + acol]);
      ((bf16x8*)WF)[(size_t)nb * 1024 + idx] = vv;
    }
  }
}

// Fused (unchanged from R6 — known-passing reference for the probes)
__global__ __launch_bounds__(512, 4) void fused_kernel(
    const float* __restrict__ enc, const unsigned short* __restrict__ WF,
    const float* __restrict__ qpart, const float* __restrict__ v,
    const int* __restrict__ mask,
    float* __restrict__ rawscore, float* __restrict__ ctxp,
    float* __restrict__ mbuf) {
  __shared__ __align__(16) unsigned short Atile[64 * 512];  // 64 KB
  __shared__ float spart[8][64];
  __shared__ float wrow[64];
  const int b = blockIdx.y, chunk = blockIdx.x;
  const int s0 = chunk * 64;
  const int tid = threadIdx.x;
  const int w = tid >> 6, lane = tid & 63;
  const int quad = lane >> 4, l16 = lane & 15;
  const int n0 = w * 64;

  const int rbase = tid >> 4;
  const int c4 = tid & 15;
  const int sw3 = (rbase & 7) << 3;
  const float4* src4 = (const float4*)(enc + ((size_t)b * SS + s0) * EE);
  const float4* g0 = src4 + rbase * 128 + c4;
  const float4* g1 = g0 + 32 * 128;
  unsigned short* st0 = &Atile[rbase * 512 + ((c4 * 4) ^ sw3)];
  unsigned short* st1 = st0 + 32 * 512;

  const bf16x8* wfl = (const bf16x8*)WF + lane;

  f32x4 acc[4][4];
#pragma unroll
  for (int m = 0; m < 4; ++m)
#pragma unroll
    for (int j = 0; j < 4; ++j) acc[m][j] = (f32x4){0.f, 0.f, 0.f, 0.f};

  float4 rb[2][2];
  rb[0][0] = g0[0]; rb[0][1] = g1[0];

#pragma unroll
  for (int c = 0; c < 8; ++c) {
    const int cur = c & 1;
    {
      float4 x = rb[cur][0];
      u16x4 p;
      p.x = f2bf(x.x); p.y = f2bf(x.y); p.z = f2bf(x.z); p.w = f2bf(x.w);
      *(u16x4*)(st0 + c * 64) = p;
      float4 y = rb[cur][1];
      u16x4 p2;
      p2.x = f2bf(y.x); p2.y = f2bf(y.y); p2.z = f2bf(y.z); p2.w = f2bf(y.w);
      *(u16x4*)(st1 + c * 64) = p2;
    }
    if (c + 1 < 8) {
      rb[cur ^ 1][0] = g0[(c + 1) * 16];
      rb[cur ^ 1][1] = g1[(c + 1) * 16];
    }
    asm volatile("s_waitcnt lgkmcnt(0)" ::: "memory");
    __builtin_amdgcn_s_barrier();
#pragma unroll
    for (int kk = 0; kk < 2; ++kk) {
      const int k0 = c * 64 + kk * 32;
      bf16x8 aF[4];
#pragma unroll
      for (int m = 0; m < 4; ++m) {
        const int row = m * 16 + l16;
        aF[m] = *(const bf16x8*)&Atile[row * 512 +
                                       ((k0 + quad * 8) ^ ((row & 7) << 3))];
      }
#pragma unroll
      for (int j = 0; j < 4; ++j) {
        bf16x8 bF = wfl[(size_t)(((w * 4 + j) * 16 + c * 2 + kk) * 64)];
#pragma unroll
        for (int m = 0; m < 4; ++m)
          acc[m][j] = __builtin_amdgcn_mfma_f32_16x16x32_bf16(aF[m], bF,
                                                              acc[m][j], 0, 0, 0);
      }
    }
  }

  float srow[4][4];
#pragma unroll
  for (int m = 0; m < 4; ++m)
#pragma unroll
    for (int r = 0; r < 4; ++r) srow[m][r] = 0.f;
#pragma unroll
  for (int j = 0; j < 4; ++j) {
    const float* qp = qpart + (size_t)b * 8 * AA + n0 + j * 16 + l16;
    float qn = 0.f;
#pragma unroll
    for (int sl = 0; sl < 8; ++sl) qn += qp[sl * AA];
    float vn = v[n0 + j * 16 + l16];
#pragma unroll
    for (int m = 0; m < 4; ++m)
#pragma unroll
      for (int r = 0; r < 4; ++r)
        srow[m][r] += tanh_fast(qn + acc[m][j][r]) * vn;
  }
#pragma unroll
  for (int m = 0; m < 4; ++m)
#pragma unroll
    for (int r = 0; r < 4; ++r) {
      float s = srow[m][r];
      s += __shfl_xor(s, 1, 64);
      s += __shfl_xor(s, 2, 64);
      s += __shfl_xor(s, 4, 64);
      s += __shfl_xor(s, 8, 64);
      if (l16 == 0) spart[w][m * 16 + quad * 4 + r] = s;
    }
  __syncthreads();

  if (tid < 64) {
    float raw = 0.f;
#pragma unroll
    for (int ww = 0; ww < 8; ++ww) raw += spart[ww][tid];
    float sc = mask[(size_t)b * SS + s0 + tid] ? -1e9f : raw;
    rawscore[(size_t)b * SS + s0 + tid] = sc;
    float mx = sc;
    for (int off = 1; off < 64; off <<= 1)
      mx = fmaxf(mx, __shfl_xor(mx, off, 64));
    wrow[tid] = __expf(sc - mx);
    if (tid == 0) mbuf[b * 64 + chunk] = mx;
  }
  __syncthreads();

  {
    const int e = tid;
    float a = 0.f;
#pragma unroll 8
    for (int row = 0; row < 64; ++row)
      a += wrow[row] * bf2f(Atile[row * 512 + (e ^ ((row & 7) << 3))]);
    ctxp[((size_t)b * 64 + chunk) * EE + e] = a;
  }
}

// Finalize (unchanged from R6)
__global__ __launch_bounds__(512) void finalize_kernel(
    float* __restrict__ attn, const float* __restrict__ ctxp,
    const float* __restrict__ mbuf, float* __restrict__ ctx) {
  __shared__ float red[16];
  __shared__ float fc[64];
  int b = blockIdx.x, t = threadIdx.x;
  float* row = attn + (size_t)b * SS;
  float vals[8];
  float m = -3e38f;
#pragma unroll
  for (int i = 0; i < 8; ++i) {
    float x = row[i * 512 + t];
    vals[i] = x;
    m = fmaxf(m, x);
  }
  for (int off = 1; off < 64; off <<= 1) m = fmaxf(m, __shfl_xor(m, off, 64));
  int wv = t >> 6, ln = t & 63;
  if (ln == 0) red[wv] = m;
  __syncthreads();
  m = red[0];
#pragma unroll
  for (int i = 1; i < 8; ++i) m = fmaxf(m, red[i]);
  float sum = 0.f;
#pragma unroll
  for (int i = 0; i < 8; ++i) { vals[i] = __expf(vals[i] - m); sum += vals[i]; }
  for (int off = 1; off < 64; off <<= 1) sum += __shfl_xor(sum, off, 64);
  if (ln == 0) red[8 + wv] = sum;
  __syncthreads();
  sum = 0.f;
#pragma unroll
  for (int i = 0; i < 8; ++i) sum += red[8 + i];
  float inv = 1.f / sum;
#pragma unroll
  for (int i = 0; i < 8; ++i) row[i * 512 + t] = vals[i] * inv;

  if (t < 64) fc[t] = __expf(mbuf[b * 64 + t] - m) * inv;
  __syncthreads();
  {
    const float* p = ctxp + (size_t)b * 64 * EE + t;
    float s = 0.f;
#pragma unroll
    for (int c = 0; c < 64; ++c) s += fc[c] * p[c * EE];
    ctx[b * EE + t] = s;
  }
}

// ===================== DIAGNOSTIC PROBES (write pscr only) =====================
// P1: staging phase exactly as fused (prefetch, f2bf, ds_write, lgkm+barrier
// per chunk), x8 reps over rotated chunks. dur/8 = stage-phase cost.
__global__ __launch_bounds__(512, 4) void probe_stage(
    const float* __restrict__ enc, float* __restrict__ pscr) {
  __shared__ __align__(16) unsigned short Atile[64 * 512];
  const int b = blockIdx.y, chunk = blockIdx.x;
  const int tid = threadIdx.x;
  const int rbase = tid >> 4, c4 = tid & 15;
  const int sw3 = (rbase & 7) << 3;
  unsigned short* st0 = &Atile[rbase * 512 + ((c4 * 4) ^ sw3)];
  unsigned short* st1 = st0 + 32 * 512;
  for (int rep = 0; rep < 8; ++rep) {
    const int ch = (chunk + rep * 9) & 63;
    const float4* g0 =
        (const float4*)(enc + ((size_t)b * SS + ch * 64) * EE) + rbase * 128 + c4;
    const float4* g1 = g0 + 32 * 128;
    float4 rb[2][2];
    rb[0][0] = g0[0]; rb[0][1] = g1[0];
#pragma unroll
    for (int c = 0; c < 8; ++c) {
      const int cur = c & 1;
      float4 x = rb[cur][0];
      u16x4 p;
      p.x = f2bf(x.x); p.y = f2bf(x.y); p.z = f2bf(x.z); p.w = f2bf(x.w);
      *(u16x4*)(st0 + c * 64) = p;
      float4 y = rb[cur][1];
      u16x4 p2;
      p2.x = f2bf(y.x); p2.y = f2bf(y.y); p2.z = f2bf(y.z); p2.w = f2bf(y.w);
      *(u16x4*)(st1 + c * 64) = p2;
      if (c + 1 < 8) {
        rb[cur ^ 1][0] = g0[(c + 1) * 16];
        rb[cur ^ 1][1] = g1[(c + 1) * 16];
      }
      asm volatile("s_waitcnt lgkmcnt(0)" ::: "memory");
      __builtin_amdgcn_s_barrier();
    }
  }
  __syncthreads();
  pscr[((size_t)b * 64 + chunk) * 512 + tid] =
      bf2f(Atile[tid * 64 + (tid & 63)]);
}

// P3: identical staging, NO per-chunk waits/barriers (compiler-fence per rep
// keeps stores live). P1 vs P3 separates barrier-coupling from issue-path.
__global__ __launch_bounds__(512, 4) void probe_stage_nobar(
    const float* __restrict__ enc, float* __restrict__ pscr) {
  __shared__ __align__(16) unsigned short Atile[64 * 512];
  const int b = blockIdx.y, chunk = blockIdx.x;
  const int tid = threadIdx.x;
  const int rbase = tid >> 4, c4 = tid & 15;
  const int sw3 = (rbase & 7) << 3;
  unsigned short* st0 = &Atile[rbase * 512 + ((c4 * 4) ^ sw3)];
  unsigned short* st1 = st0 + 32 * 512;
  for (int rep = 0; rep < 8; ++rep) {
    const int ch = (chunk + rep * 9) & 63;
    const float4* g0 =
        (const float4*)(enc + ((size_t)b * SS + ch * 64) * EE) + rbase * 128 + c4;
    const float4* g1 = g0 + 32 * 128;
    float4 rb[2][2];
    rb[0][0] = g0[0]; rb[0][1] = g1[0];
#pragma unroll
    for (int c = 0; c < 8; ++c) {
      const int cur = c & 1;
      float4 x = rb[cur][0];
      u16x4 p;
      p.x = f2bf(x.x); p.y = f2bf(x.y); p.z = f2bf(x.z); p.w = f2bf(x.w);
      *(u16x4*)(st0 + c * 64) = p;
      float4 y = rb[cur][1];
      u16x4 p2;
      p2.x = f2bf(y.x); p2.y = f2bf(y.y); p2.z = f2bf(y.z); p2.w = f2bf(y.w);
      *(u16x4*)(st1 + c * 64) = p2;
      if (c + 1 < 8) {
        rb[cur ^ 1][0] = g0[(c + 1) * 16];
        rb[cur ^ 1][1] = g1[(c + 1) * 16];
      }
    }
    asm volatile("" ::: "memory");   // keep per-rep stores (no instruction)
  }
  __syncthreads();
  pscr[((size_t)b * 64 + chunk) * 512 + tid] =
      bf2f(Atile[tid * 64 + (tid & 63)]);
}

// P2: stage once, then x8 reps of the barrier+MFMA sweep (LDS + L2-hot WF,
// no enc traffic). dur - stage_once ≈ 8x compute-phase cost.
__global__ __launch_bounds__(512, 4) void probe_mfma(
    const float* __restrict__ enc, const unsigned short* __restrict__ WF,
    float* __restrict__ pscr) {
  __shared__ __align__(16) unsigned short Atile[64 * 512];
  const int b = blockIdx.y, chunk = blockIdx.x;
  const int tid = threadIdx.x;
  const int w = tid >> 6, lane = tid & 63;
  const int quad = lane >> 4, l16 = lane & 15;
  const int rbase = tid >> 4, c4 = tid & 15;
  const int sw3 = (rbase & 7) << 3;
  unsigned short* st0 = &Atile[rbase * 512 + ((c4 * 4) ^ sw3)];
  unsigned short* st1 = st0 + 32 * 512;
  {
    const float4* g0 =
        (const float4*)(enc + ((size_t)b * SS + chunk * 64) * EE) + rbase * 128 + c4;
    const float4* g1 = g0 + 32 * 128;
#pragma unroll
    for (int c = 0; c < 8; ++c) {
      float4 x = g0[c * 16];
      u16x4 p;
      p.x = f2bf(x.x); p.y = f2bf(x.y); p.z = f2bf(x.z); p.w = f2bf(x.w);
      *(u16x4*)(st0 + c * 64) = p;
      float4 y = g1[c * 16];
      u16x4 p2;
      p2.x = f2bf(y.x); p2.y = f2bf(y.y); p2.z = f2bf(y.z); p2.w = f2bf(y.w);
      *(u16x4*)(st1 + c * 64) = p2;
    }
  }
  __syncthreads();
  const bf16x8* wfl = (const bf16x8*)WF + lane;
  f32x4 acc[4][4];
#pragma unroll
  for (int m = 0; m < 4; ++m)
#pragma unroll
    for (int j = 0; j < 4; ++j) acc[m][j] = (f32x4){0.f, 0.f, 0.f, 0.f};
  for (int rep = 0; rep < 8; ++rep) {
#pragma unroll
    for (int c = 0; c < 8; ++c) {
      __builtin_amdgcn_s_barrier();
#pragma unroll
      for (int kk = 0; kk < 2; ++kk) {
        const int k0 = c * 64 + kk * 32;
        bf16x8 aF[4];
#pragma unroll
        for (int m = 0; m < 4; ++m) {
          const int row = m * 16 + l16;
          aF[m] = *(const bf16x8*)&Atile[row * 512 +
                                         ((k0 + quad * 8) ^ ((row & 7) << 3))];
        }
#pragma unroll
        for (int j = 0; j < 4; ++j) {
          bf16x8 bF = wfl[(size_t)(((w * 4 + j) * 16 + c * 2 + kk) * 64)];
#pragma unroll
          for (int m = 0; m < 4; ++m)
            acc[m][j] = __builtin_amdgcn_mfma_f32_16x16x32_bf16(aF[m], bF,
                                                                acc[m][j], 0, 0, 0);
        }
      }
    }
  }
  float csum = 0.f;
#pragma unroll
  for (int m = 0; m < 4; ++m)
#pragma unroll
    for (int j = 0; j < 4; ++j)
#pragma unroll
      for (int r = 0; r < 4; ++r) csum += acc[m][j][r];
  pscr[((size_t)b * 64 + chunk) * 512 + tid] = csum;
}

extern "C" void kernel_launch(void* const* d_in, const int* in_sizes, int n_in,
                              void* d_out, int out_size, void* d_ws, size_t ws_size,
                              hipStream_t stream) {
  const float* h    = (const float*)d_in[0];
  const float* enc  = (const float*)d_in[1];
  const int*   mask = (const int*)d_in[2];
  const float* Wh   = (const float*)d_in[3];
  const float* Ws   = (const float*)d_in[4];
  const float* v    = (const float*)d_in[5];

  float* out  = (float*)d_out;
  float* ctx  = out;              // [32,512]
  float* attn = out + BB * EE;    // [32,4096]

  char* ws = (char*)d_ws;
  float* qpart = (float*)ws;                 ws += (size_t)BB * 8 * AA * 4;    // 512 KB
  unsigned short* WF = (unsigned short*)ws;  ws += (size_t)AA * EE * 2;        // 512 KB
  float* ctxp = (float*)ws;                  ws += (size_t)BB * 64 * EE * 4;   // 4 MB
  float* mbuf = (float*)ws;                  ws += (size_t)BB * 64 * 4;        // 8 KB
  float* pscr = (float*)ws;                                                    // 4 MB

  hipLaunchKernelGGL(prep_kernel, dim3(288), dim3(512), 0, stream,
                     h, Wh, Ws, qpart, WF);
  hipLaunchKernelGGL(fused_kernel, dim3(SS / 64, BB), dim3(512), 0, stream,
                     enc, WF, qpart, v, mask, attn, ctxp, mbuf);
  hipLaunchKernelGGL(finalize_kernel, dim3(BB), dim3(512), 0, stream,
                     attn, ctxp, mbuf, ctx);
  // ---- diagnostic probes (after real pipeline; write pscr only) ----
  hipLaunchKernelGGL(probe_stage, dim3(SS / 64, BB), dim3(512), 0, stream,
                     enc, pscr);
  hipLaunchKernelGGL(probe_mfma, dim3(SS / 64, BB), dim3(512), 0, stream,
                     enc, WF, pscr);
  hipLaunchKernelGGL(probe_stage_nobar, dim3(SS / 64, BB), dim3(512), 0, stream,
                     enc, pscr);
}